// Round 13
// baseline (109.833 us; speedup 1.0000x reference)
//
#include <hip/hip_runtime.h>
#include <hip/hip_fp16.h>
#include <math.h>

// Problem constants (fixed by reference)
#define BATCH 2
#define SEQ   4096
#define DIN   128
#define NH    8
#define DHD   16
#define MROWS (BATCH * SEQ)   // 8192
#define QSCALE 0.36067376022224085f   // 0.25 * log2(e): scores in log2-domain
// lengths = {4096, 3072}, both multiples of 128.

typedef _Float16 h4 __attribute__((ext_vector_type(4)));
typedef _Float16 h8 __attribute__((ext_vector_type(8)));
typedef float    f4 __attribute__((ext_vector_type(4)));

typedef union { h8 v; unsigned u[4]; } H8U;

__device__ __forceinline__ int keyperm(int k) {
    return ((k >> 5) & 1) * 32 + ((k >> 2) & 3) * 8 + ((k >> 4) & 1) * 4 + (k & 3);
}

// ---------------------------------------------------------------------------
// Kernel 1: projection — R17 structure (128x128 tiles, 256 blocks, W loaded
// once per (region,rowblk)). regions: 0=q 1=k 2=out-init 3=v(keyperm).
// ---------------------------------------------------------------------------
__global__ __launch_bounds__(512) void proj_kernel(
    const float* __restrict__ x, const int* __restrict__ mask,
    const float* __restrict__ W1, const float* __restrict__ Wv,
    const float* __restrict__ b1, const float* __restrict__ bv,
    const float* __restrict__ bo,
    _Float16* __restrict__ qT, _Float16* __restrict__ kT,
    _Float16* __restrict__ vT4, float* __restrict__ out)
{
    __shared__ __align__(16) char SMEM[128 * 136 * 2];
    _Float16* Tw  = (_Float16*)SMEM;   // [128][136] weight slice (transposed)
    _Float16* T16 = (_Float16*)SMEM;   // [128][136] epilogue staging (q/k/v)

    const int t = threadIdx.x;
    const int w = t >> 6, lane = t & 63, quad = lane >> 4, mr = lane & 15;
    const int flat   = blockIdx.x + 4 * blockIdx.y;   // hw linear wg id
    const int region = flat >> 6;            // 0=q 1=k 2=out-init 3=v
    const int row0   = (flat & 63) * 128;
    const int col0   = region * 128;

    if (mask[row0] == 0) {
        if (region == 2) {                   // zero the out tile (masked rows)
#pragma unroll
            for (int i = 0; i < 8; ++i) {
                int idx = t + i * 512;       // r(128) x c4(32)
                int r = idx >> 5, c4 = idx & 31;
                *reinterpret_cast<float4*>(
                    out + (size_t)(row0 + r) * 128 + c4 * 4) =
                    (float4){0.f, 0.f, 0.f, 0.f};
            }
        }
        return;
    }

    // Batch-issue ALL global loads first: 8 W float4 + 8 x float4 per thread.
    const float* wsrc = (region < 3) ? (W1 + col0) : Wv;
    const int wstride = (region < 3) ? 384 : 128;
    float4 wv[8];
#pragma unroll
    for (int i = 0; i < 8; ++i) {
        int idx = t + i * 512;               // k(128) x c4(32)
        int k = idx >> 5, c4 = idx & 31;
        wv[i] = *reinterpret_cast<const float4*>(wsrc + (size_t)k * wstride + c4 * 4);
    }
    float4 xv[8];
    {
        const float* xrow = x + (size_t)(row0 + w * 16 + mr) * 128;
#pragma unroll
        for (int ks = 0; ks < 4; ++ks) {
            xv[2 * ks]     = *reinterpret_cast<const float4*>(xrow + ks * 32 + quad * 8);
            xv[2 * ks + 1] = *reinterpret_cast<const float4*>(xrow + ks * 32 + quad * 8 + 4);
        }
    }

    // Convert W -> LDS (transposed)
#pragma unroll
    for (int i = 0; i < 8; ++i) {
        int idx = t + i * 512;
        int k = idx >> 5, c4 = idx & 31;
        Tw[(c4 * 4 + 0) * 136 + k] = (_Float16)wv[i].x;
        Tw[(c4 * 4 + 1) * 136 + k] = (_Float16)wv[i].y;
        Tw[(c4 * 4 + 2) * 136 + k] = (_Float16)wv[i].z;
        Tw[(c4 * 4 + 3) * 136 + k] = (_Float16)wv[i].w;
    }
    // Convert x -> A fragments
    h8 a[4];
#pragma unroll
    for (int ks = 0; ks < 4; ++ks) {
        h8 av;
        av[0] = (_Float16)xv[2*ks].x;   av[1] = (_Float16)xv[2*ks].y;
        av[2] = (_Float16)xv[2*ks].z;   av[3] = (_Float16)xv[2*ks].w;
        av[4] = (_Float16)xv[2*ks+1].x; av[5] = (_Float16)xv[2*ks+1].y;
        av[6] = (_Float16)xv[2*ks+1].z; av[7] = (_Float16)xv[2*ks+1].w;
        a[ks] = av;
    }
    __syncthreads();

    f4 acc[8];
#pragma unroll
    for (int ct = 0; ct < 8; ++ct) {
        f4 ac = {0.f, 0.f, 0.f, 0.f};
#pragma unroll
        for (int ks = 0; ks < 4; ++ks) {
            h8 bb = *reinterpret_cast<const h8*>(
                &Tw[(ct * 16 + mr) * 136 + ks * 32 + quad * 8]);
            ac = __builtin_amdgcn_mfma_f32_16x16x32_f16(a[ks], bb, ac, 0, 0, 0);
        }
        acc[ct] = ac;
    }
    __syncthreads();   // Tw reads done before staging overwrites

    if (region <= 1) {               // q (pre-scaled) or k -> [h][m][16]
        float scale = (region == 0) ? QSCALE : 1.0f;
#pragma unroll
        for (int ct = 0; ct < 8; ++ct) {
            float bias = b1[col0 + ct * 16 + mr];
#pragma unroll
            for (int reg = 0; reg < 4; ++reg) {
                int lr = w * 16 + quad * 4 + reg;
                T16[lr * 136 + ct * 16 + mr] =
                    (_Float16)((acc[ct][reg] + bias) * scale);
            }
        }
        __syncthreads();
        _Float16* dstbase = (region == 0) ? qT : kT;
#pragma unroll
        for (int i = 0; i < 4; ++i) {
            int idx = t + i * 512;           // h(8) x rr(128) x half(2)
            int h = idx >> 8, rr = (idx >> 1) & 127, half = idx & 1;
            *reinterpret_cast<h8*>(
                dstbase + ((size_t)h * MROWS + row0 + rr) * 16 + half * 8) =
                *reinterpret_cast<h8*>(&T16[rr * 136 + h * 16 + half * 8]);
        }
    } else if (region == 2) {        // out-init: mask*(non_att + b1' + bo), f32
#pragma unroll
        for (int ct = 0; ct < 8; ++ct) {
            float bias = b1[256 + ct * 16 + mr] + bo[ct * 16 + mr];
#pragma unroll
            for (int reg = 0; reg < 4; ++reg) {
                int lr = w * 16 + quad * 4 + reg;
                out[(size_t)(row0 + lr) * 128 + ct * 16 + mr] =
                    acc[ct][reg] + bias;
            }
        }
    } else {                         // v -> vT4[h][tile][d][keyperm]
#pragma unroll
        for (int ct = 0; ct < 8; ++ct) {
            float bias = bv[ct * 16 + mr];
#pragma unroll
            for (int reg = 0; reg < 4; ++reg) {
                int m = w * 16 + quad * 4 + reg;
                int sub = m >> 6, ml = m & 63;
                T16[(ct * 16 + mr) * 136 + sub * 64 + keyperm(ml)] =
                    (_Float16)(acc[ct][reg] + bias);
            }
        }
        __syncthreads();
#pragma unroll
        for (int i = 0; i < 4; ++i) {
            int idx = t + i * 512;           // c(128) x sub(2) x seg(8)
            int c = idx >> 4, sub = (idx >> 3) & 1, seg = idx & 7;
            int h = c >> 4, d = c & 15;
            int tile = (flat & 63) * 2 + sub;
            *reinterpret_cast<h8*>(
                vT4 + ((size_t)(h * 128 + tile) * 16 + d) * 64 + seg * 8) =
                *reinterpret_cast<h8*>(&T16[c * 136 + sub * 64 + seg * 8]);
        }
    }
}

// ---------------------------------------------------------------------------
// Kernel 2: flash attention — EXACT R21 structure (best measured: 109.5 total).
// 4 chains/wave, head-pinned XCD swizzle, setprio, 3-slot LDS combine.
// R22 (occupancy at fixed ILP) and R23 (stagger + VGPR headroom) both null:
// attn is at its practical plateau for this structure — frozen.
// ---------------------------------------------------------------------------
#define LOADT(K0, K1, K2, K3, V0, V1, TILE)                                   \
    do {                                                                      \
        const _Float16* kp_ = kbase + (size_t)(TILE) * 1024;                  \
        const _Float16* vp_ = vbase + (size_t)(TILE) * 1024;                  \
        K0 = *reinterpret_cast<const h4*>(kp_);                               \
        K1 = *reinterpret_cast<const h4*>(kp_ + 256);                         \
        K2 = *reinterpret_cast<const h4*>(kp_ + 512);                         \
        K3 = *reinterpret_cast<const h4*>(kp_ + 768);                         \
        V0 = *reinterpret_cast<const h8*>(vp_);                               \
        V1 = *reinterpret_cast<const h8*>(vp_ + 32);                         \
    } while (0)

#define PROC_SUB(AQ, K0, K1, K2, K3, V0, V1, O, L)                            \
    do {                                                                      \
        f4 st0 = __builtin_amdgcn_mfma_f32_16x16x16f16(K0, AQ, fzero, 0, 0, 0); \
        f4 st1 = __builtin_amdgcn_mfma_f32_16x16x16f16(K1, AQ, fzero, 0, 0, 0); \
        f4 st2 = __builtin_amdgcn_mfma_f32_16x16x16f16(K2, AQ, fzero, 0, 0, 0); \
        f4 st3 = __builtin_amdgcn_mfma_f32_16x16x16f16(K3, AQ, fzero, 0, 0, 0); \
        H8U pa, pb;                                                           \
        pa.u[0] = __builtin_bit_cast(unsigned, __builtin_amdgcn_cvt_pkrtz(    \
            __builtin_amdgcn_exp2f(st0[0]), __builtin_amdgcn_exp2f(st0[1]))); \
        pa.u[1] = __builtin_bit_cast(unsigned, __builtin_amdgcn_cvt_pkrtz(    \
            __builtin_amdgcn_exp2f(st0[2]), __builtin_amdgcn_exp2f(st0[3]))); \
        pa.u[2] = __builtin_bit_cast(unsigned, __builtin_amdgcn_cvt_pkrtz(    \
            __builtin_amdgcn_exp2f(st1[0]), __builtin_amdgcn_exp2f(st1[1]))); \
        pa.u[3] = __builtin_bit_cast(unsigned, __builtin_amdgcn_cvt_pkrtz(    \
            __builtin_amdgcn_exp2f(st1[2]), __builtin_amdgcn_exp2f(st1[3]))); \
        pb.u[0] = __builtin_bit_cast(unsigned, __builtin_amdgcn_cvt_pkrtz(    \
            __builtin_amdgcn_exp2f(st2[0]), __builtin_amdgcn_exp2f(st2[1]))); \
        pb.u[1] = __builtin_bit_cast(unsigned, __builtin_amdgcn_cvt_pkrtz(    \
            __builtin_amdgcn_exp2f(st2[2]), __builtin_amdgcn_exp2f(st2[3]))); \
        pb.u[2] = __builtin_bit_cast(unsigned, __builtin_amdgcn_cvt_pkrtz(    \
            __builtin_amdgcn_exp2f(st3[0]), __builtin_amdgcn_exp2f(st3[1]))); \
        pb.u[3] = __builtin_bit_cast(unsigned, __builtin_amdgcn_cvt_pkrtz(    \
            __builtin_amdgcn_exp2f(st3[2]), __builtin_amdgcn_exp2f(st3[3]))); \
        O = __builtin_amdgcn_mfma_f32_16x16x32_f16(pa.v, V0, O, 0, 0, 0);     \
        L = __builtin_amdgcn_mfma_f32_16x16x32_f16(pa.v, vones, L, 0, 0, 0);  \
        O = __builtin_amdgcn_mfma_f32_16x16x32_f16(pb.v, V1, O, 0, 0, 0);     \
        L = __builtin_amdgcn_mfma_f32_16x16x32_f16(pb.v, vones, L, 0, 0, 0);  \
    } while (0)

#define COMBINE(OC, LC, CIDX)                                                 \
    do {                                                                      \
        _Pragma("unroll")                                                     \
        for (int reg = 0; reg < 4; ++reg) {                                   \
            float of = OC[reg] + Cmb[0][wq][lane][(CIDX)*4 + reg]             \
                               + Cmb[1][wq][lane][(CIDX)*4 + reg]             \
                               + Cmb[2][wq][lane][(CIDX)*4 + reg];            \
            float lf = LC[reg] + Cmb[0][wq][lane][16 + (CIDX)*4 + reg]        \
                               + Cmb[1][wq][lane][16 + (CIDX)*4 + reg]        \
                               + Cmb[2][wq][lane][16 + (CIDX)*4 + reg];       \
            att16[(size_t)(m0 + (CIDX)*16 + quad * 4 + reg) * 128             \
                  + hh * DHD + mr] = (_Float16)(of / lf);                     \
        }                                                                     \
    } while (0)

__global__ __launch_bounds__(512) void attn_kernel(
    const _Float16* __restrict__ qT, const _Float16* __restrict__ kT,
    const _Float16* __restrict__ vT4, const int* __restrict__ mask,
    _Float16* __restrict__ att16)
{
    __shared__ float Cmb[3][2][64][33];   // 3 writer groups x wq x lane x 32+pad

    // XCD swizzle: hw linear wg id; xcd slot = flat%8 == hh (K/V L2 locality).
    const int flat = blockIdx.x + 32 * blockIdx.y + 256 * blockIdx.z;
    const int hh = flat & 7;
    const int qt = (flat >> 3) & 31;
    const int b  = flat >> 8;

    const int t = threadIdx.x;
    const int w = t >> 6, lane = t & 63, quad = lane >> 4, mr = lane & 15;
    const int wq = w & 1;          // q sub-tile (64 rows each)
    const int g  = w >> 1;         // key-range quarter (0..3)
    const int m0 = b * SEQ + qt * 128 + wq * 64;

    if (mask[b * SEQ + qt * 128] == 0) return;

    int tv = mask[b * SEQ + lane * 64];
    const int ntiles = (int)__popcll(__ballot(tv != 0));   // 64 or 48
    const int quarter = ntiles >> 2;                        // 16 or 12 (even)
    const int tbeg = g * quarter;
    const int tend = tbeg + quarter;

    const h4 aQ0 = *reinterpret_cast<const h4*>(
        qT + ((size_t)hh * MROWS + m0 + mr) * DHD + quad * 4);
    const h4 aQ1 = *reinterpret_cast<const h4*>(
        qT + ((size_t)hh * MROWS + m0 + 16 + mr) * DHD + quad * 4);
    const h4 aQ2 = *reinterpret_cast<const h4*>(
        qT + ((size_t)hh * MROWS + m0 + 32 + mr) * DHD + quad * 4);
    const h4 aQ3 = *reinterpret_cast<const h4*>(
        qT + ((size_t)hh * MROWS + m0 + 48 + mr) * DHD + quad * 4);

    const _Float16* kbase = kT + ((size_t)hh * MROWS + b * SEQ + mr) * DHD + quad * 4;
    const _Float16* vbase = vT4 + ((size_t)(hh * 128 + b * 64) * 16 + mr) * 64 + quad * 8;

    const f4 fzero = {0.f, 0.f, 0.f, 0.f};
    const _Float16 one = (_Float16)1.0f;
    const h8 vones = {one, one, one, one, one, one, one, one};

    h4 ka0, ka1, ka2, ka3, kb0, kb1, kb2, kb3;
    h8 va0, va1, vb0, vb1;
    LOADT(ka0, ka1, ka2, ka3, va0, va1, tbeg);
    LOADT(kb0, kb1, kb2, kb3, vb0, vb1, tbeg + 1);

    f4 O0 = fzero, O1 = fzero, O2 = fzero, O3 = fzero;
    f4 L0 = fzero, L1 = fzero, L2 = fzero, L3 = fzero;

    for (int it = tbeg; it < tend; it += 2) {
        __builtin_amdgcn_s_setprio(1);
        PROC_SUB(aQ0, ka0, ka1, ka2, ka3, va0, va1, O0, L0);
        PROC_SUB(aQ1, ka0, ka1, ka2, ka3, va0, va1, O1, L1);
        PROC_SUB(aQ2, ka0, ka1, ka2, ka3, va0, va1, O2, L2);
        PROC_SUB(aQ3, ka0, ka1, ka2, ka3, va0, va1, O3, L3);
        __builtin_amdgcn_s_setprio(0);
        int nA = (it + 2 < tend) ? (it + 2) : it;
        LOADT(ka0, ka1, ka2, ka3, va0, va1, nA);

        __builtin_amdgcn_s_setprio(1);
        PROC_SUB(aQ0, kb0, kb1, kb2, kb3, vb0, vb1, O0, L0);
        PROC_SUB(aQ1, kb0, kb1, kb2, kb3, vb0, vb1, O1, L1);
        PROC_SUB(aQ2, kb0, kb1, kb2, kb3, vb0, vb1, O2, L2);
        PROC_SUB(aQ3, kb0, kb1, kb2, kb3, vb0, vb1, O3, L3);
        __builtin_amdgcn_s_setprio(0);
        int nB = (it + 3 < tend) ? (it + 3) : (it + 1);
        LOADT(kb0, kb1, kb2, kb3, vb0, vb1, nB);
    }

    if (g != 0) {
        float* dst = &Cmb[g - 1][wq][lane][0];
#pragma unroll
        for (int reg = 0; reg < 4; ++reg) {
            dst[reg]      = O0[reg];
            dst[4 + reg]  = O1[reg];
            dst[8 + reg]  = O2[reg];
            dst[12 + reg] = O3[reg];
            dst[16 + reg] = L0[reg];
            dst[20 + reg] = L1[reg];
            dst[24 + reg] = L2[reg];
            dst[28 + reg] = L3[reg];
        }
    }
    __syncthreads();
    if (g == 0) {
        COMBINE(O0, L0, 0);
        COMBINE(O1, L1, 1);
        COMBINE(O2, L2, 2);
        COMBINE(O3, L3, 3);
    }
}

// ---------------------------------------------------------------------------
// Kernel 3: out += att16 @ Wo. R24: isolated A/B of the 1024-block shape
// (R20 bundled it with the proj regression; never tested alone). 64r x 16c
// per block, 256 threads x 4 waves -> 4 blocks/CU, 16 waves/CU (was 8).
// No per-block fixed-cost amplification: Wo slice halves with block count.
// ---------------------------------------------------------------------------
__global__ __launch_bounds__(256) void outproj_kernel(
    const _Float16* __restrict__ att16, const float* __restrict__ Wo,
    const int* __restrict__ mask, float* __restrict__ out)
{
    __shared__ __align__(16) _Float16 Tw[16 * 136];   // Wo 128k x 16c slice, transposed

    const int t = threadIdx.x;
    const int w = t >> 6, lane = t & 63, quad = lane >> 4, mr = lane & 15;
    const int row0 = blockIdx.x * 64;
    const int m0w  = row0 + w * 16;
    const int c0   = blockIdx.y * 16;

    if (mask[row0] == 0) return;     // out already zeroed by proj out-init

    // Wo slice (128k x 16c) -> Tw[c][k] f16, batched loads (2 float4/thread)
    float4 wv[2];
#pragma unroll
    for (int i = 0; i < 2; ++i) {
        int idx = t + i * 256;               // k(128) x c4(4)
        int k = idx >> 2, c4 = idx & 3;
        wv[i] = *reinterpret_cast<const float4*>(Wo + (size_t)k * 128 + c0 + c4 * 4);
    }
    h8 a[4];
#pragma unroll
    for (int ks = 0; ks < 4; ++ks)
        a[ks] = *reinterpret_cast<const h8*>(
            att16 + (size_t)(m0w + mr) * 128 + ks * 32 + quad * 8);
#pragma unroll
    for (int i = 0; i < 2; ++i) {
        int idx = t + i * 256;
        int k = idx >> 2, c4 = idx & 3;
        Tw[(c4 * 4 + 0) * 136 + k] = (_Float16)wv[i].x;
        Tw[(c4 * 4 + 1) * 136 + k] = (_Float16)wv[i].y;
        Tw[(c4 * 4 + 2) * 136 + k] = (_Float16)wv[i].z;
        Tw[(c4 * 4 + 3) * 136 + k] = (_Float16)wv[i].w;
    }
    __syncthreads();

    f4 ac = {0.f, 0.f, 0.f, 0.f};
#pragma unroll
    for (int ks = 0; ks < 4; ++ks) {
        h8 bb = *reinterpret_cast<const h8*>(
            &Tw[mr * 136 + ks * 32 + quad * 8]);
        ac = __builtin_amdgcn_mfma_f32_16x16x32_f16(a[ks], bb, ac, 0, 0, 0);
    }

    // out += att@Wo (single writer per element; out holds non_att + biases)
#pragma unroll
    for (int reg = 0; reg < 4; ++reg) {
        int lr = w * 16 + quad * 4 + reg;            // 0..63
        size_t idx = (size_t)(row0 + lr) * 128 + c0 + mr;
        out[idx] = out[idx] + ac[reg];
    }
}

// ---------------------------------------------------------------------------
extern "C" void kernel_launch(void* const* d_in, const int* in_sizes, int n_in,
                              void* d_out, int out_size, void* d_ws, size_t ws_size,
                              hipStream_t stream) {
    const float* x    = (const float*)d_in[0];
    const int*   mask = (const int*)  d_in[1];
    const float* W1   = (const float*)d_in[2];
    const float* b1   = (const float*)d_in[3];
    const float* Wv   = (const float*)d_in[4];
    const float* bv   = (const float*)d_in[5];
    const float* Wo   = (const float*)d_in[6];
    const float* bo   = (const float*)d_in[7];
    float* out = (float*)d_out;

    _Float16* qT    = (_Float16*)d_ws;                     // [8][8192][16] = 2 MB
    _Float16* kT    = qT    + (size_t)NH * MROWS * DHD;    //                 2 MB
    _Float16* vT4   = kT    + (size_t)NH * MROWS * DHD;    // [8][128][16][64] = 2 MB
    _Float16* att16 = vT4   + (size_t)DIN * MROWS;         // [8192][128] =   2 MB

    proj_kernel<<<dim3(4, 64), 512, 0, stream>>>(
        x, mask, W1, Wv, b1, bv, bo, qT, kT, vT4, out);
    attn_kernel<<<dim3(SEQ / 128, NH, BATCH), 512, 0, stream>>>(
        qT, kT, vT4, mask, att16);
    outproj_kernel<<<dim3(MROWS / 64, 8), 256, 0, stream>>>(
        att16, Wo, mask, out);
}

// Round 15
// 108.421 us; speedup vs baseline: 1.0130x; 1.0130x over previous
//
#include <hip/hip_runtime.h>
#include <hip/hip_fp16.h>
#include <math.h>

// Problem constants (fixed by reference)
#define BATCH 2
#define SEQ   4096
#define DIN   128
#define NH    8
#define DHD   16
#define MROWS (BATCH * SEQ)   // 8192
#define QSCALE 0.36067376022224085f   // 0.25 * log2(e): scores in log2-domain
// lengths = {4096, 3072}, both multiples of 128.

typedef _Float16 h4 __attribute__((ext_vector_type(4)));
typedef _Float16 h8 __attribute__((ext_vector_type(8)));
typedef float    f4 __attribute__((ext_vector_type(4)));

typedef union { h8 v; unsigned u[4]; } H8U;

__device__ __forceinline__ int keyperm(int k) {
    return ((k >> 5) & 1) * 32 + ((k >> 2) & 3) * 8 + ((k >> 4) & 1) * 4 + (k & 3);
}

// ---------------------------------------------------------------------------
// Kernel 1: projection — R17 structure (128x128 tiles, 256 blocks).
// R25: W->LDS transpose packed along k: load W rows 2k,2k+1 per thread,
// cvt_pkrtz pairs -> one 4B store each (32 scalar f16 stores -> 16 dword
// stores). x->fragment conversion also packed (8 scalar cvt -> 4 cvt_pkrtz).
// regions: 0=q 1=k 2=out-init 3=v(keyperm).
// ---------------------------------------------------------------------------
__global__ __launch_bounds__(512) void proj_kernel(
    const float* __restrict__ x, const int* __restrict__ mask,
    const float* __restrict__ W1, const float* __restrict__ Wv,
    const float* __restrict__ b1, const float* __restrict__ bv,
    const float* __restrict__ bo,
    _Float16* __restrict__ qT, _Float16* __restrict__ kT,
    _Float16* __restrict__ vT4, float* __restrict__ out)
{
    __shared__ __align__(16) char SMEM[128 * 136 * 2];
    _Float16* Tw  = (_Float16*)SMEM;   // [128][136] weight slice (transposed)
    _Float16* T16 = (_Float16*)SMEM;   // [128][136] epilogue staging (q/k/v)

    const int t = threadIdx.x;
    const int w = t >> 6, lane = t & 63, quad = lane >> 4, mr = lane & 15;
    const int flat   = blockIdx.x + 4 * blockIdx.y;   // hw linear wg id
    const int region = flat >> 6;            // 0=q 1=k 2=out-init 3=v
    const int row0   = (flat & 63) * 128;
    const int col0   = region * 128;

    if (mask[row0] == 0) {
        if (region == 2) {                   // zero the out tile (masked rows)
#pragma unroll
            for (int i = 0; i < 8; ++i) {
                int idx = t + i * 512;       // r(128) x c4(32)
                int r = idx >> 5, c4 = idx & 31;
                *reinterpret_cast<float4*>(
                    out + (size_t)(row0 + r) * 128 + c4 * 4) =
                    (float4){0.f, 0.f, 0.f, 0.f};
            }
        }
        return;
    }

    // Batch-issue ALL global loads first: 4 W float4-PAIRS (rows 2k,2k+1)
    // + 8 x float4 per thread.
    const float* wsrc = (region < 3) ? (W1 + col0) : Wv;
    const int wstride = (region < 3) ? 384 : 128;
    float4 wa[4], wb[4];
#pragma unroll
    for (int i = 0; i < 4; ++i) {
        int idx = t + i * 512;               // k2(64) x c4(32)
        int k2 = idx >> 5, c4 = idx & 31;
        wa[i] = *reinterpret_cast<const float4*>(wsrc + (size_t)(2 * k2)     * wstride + c4 * 4);
        wb[i] = *reinterpret_cast<const float4*>(wsrc + (size_t)(2 * k2 + 1) * wstride + c4 * 4);
    }
    float4 xv[8];
    {
        const float* xrow = x + (size_t)(row0 + w * 16 + mr) * 128;
#pragma unroll
        for (int ks = 0; ks < 4; ++ks) {
            xv[2 * ks]     = *reinterpret_cast<const float4*>(xrow + ks * 32 + quad * 8);
            xv[2 * ks + 1] = *reinterpret_cast<const float4*>(xrow + ks * 32 + quad * 8 + 4);
        }
    }

    // Convert W -> LDS (transposed), packed: h2 per store (cols adjacent in k)
#pragma unroll
    for (int i = 0; i < 4; ++i) {
        int idx = t + i * 512;
        int k2 = idx >> 5, c4 = idx & 31;
        const float* fa = reinterpret_cast<const float*>(&wa[i]);
        const float* fb = reinterpret_cast<const float*>(&wb[i]);
#pragma unroll
        for (int j = 0; j < 4; ++j) {
            unsigned p = __builtin_bit_cast(unsigned,
                __builtin_amdgcn_cvt_pkrtz(fa[j], fb[j]));   // (W[2k][c], W[2k+1][c])
            *reinterpret_cast<unsigned*>(&Tw[(c4 * 4 + j) * 136 + 2 * k2]) = p;
        }
    }
    // Convert x -> A fragments, packed
    h8 a[4];
#pragma unroll
    for (int ks = 0; ks < 4; ++ks) {
        H8U av;
        const float* f0 = reinterpret_cast<const float*>(&xv[2 * ks]);
        const float* f1 = reinterpret_cast<const float*>(&xv[2 * ks + 1]);
        av.u[0] = __builtin_bit_cast(unsigned, __builtin_amdgcn_cvt_pkrtz(f0[0], f0[1]));
        av.u[1] = __builtin_bit_cast(unsigned, __builtin_amdgcn_cvt_pkrtz(f0[2], f0[3]));
        av.u[2] = __builtin_bit_cast(unsigned, __builtin_amdgcn_cvt_pkrtz(f1[0], f1[1]));
        av.u[3] = __builtin_bit_cast(unsigned, __builtin_amdgcn_cvt_pkrtz(f1[2], f1[3]));
        a[ks] = av.v;
    }
    __syncthreads();

    f4 acc[8];
#pragma unroll
    for (int ct = 0; ct < 8; ++ct) {
        f4 ac = {0.f, 0.f, 0.f, 0.f};
#pragma unroll
        for (int ks = 0; ks < 4; ++ks) {
            h8 bb = *reinterpret_cast<const h8*>(
                &Tw[(ct * 16 + mr) * 136 + ks * 32 + quad * 8]);
            ac = __builtin_amdgcn_mfma_f32_16x16x32_f16(a[ks], bb, ac, 0, 0, 0);
        }
        acc[ct] = ac;
    }
    __syncthreads();   // Tw reads done before staging overwrites

    if (region <= 1) {               // q (pre-scaled) or k -> [h][m][16]
        float scale = (region == 0) ? QSCALE : 1.0f;
#pragma unroll
        for (int ct = 0; ct < 8; ++ct) {
            float bias = b1[col0 + ct * 16 + mr];
#pragma unroll
            for (int reg = 0; reg < 4; ++reg) {
                int lr = w * 16 + quad * 4 + reg;
                T16[lr * 136 + ct * 16 + mr] =
                    (_Float16)((acc[ct][reg] + bias) * scale);
            }
        }
        __syncthreads();
        _Float16* dstbase = (region == 0) ? qT : kT;
#pragma unroll
        for (int i = 0; i < 4; ++i) {
            int idx = t + i * 512;           // h(8) x rr(128) x half(2)
            int h = idx >> 8, rr = (idx >> 1) & 127, half = idx & 1;
            *reinterpret_cast<h8*>(
                dstbase + ((size_t)h * MROWS + row0 + rr) * 16 + half * 8) =
                *reinterpret_cast<h8*>(&T16[rr * 136 + h * 16 + half * 8]);
        }
    } else if (region == 2) {        // out-init: mask*(non_att + b1' + bo), f32
#pragma unroll
        for (int ct = 0; ct < 8; ++ct) {
            float bias = b1[256 + ct * 16 + mr] + bo[ct * 16 + mr];
#pragma unroll
            for (int reg = 0; reg < 4; ++reg) {
                int lr = w * 16 + quad * 4 + reg;
                out[(size_t)(row0 + lr) * 128 + ct * 16 + mr] =
                    acc[ct][reg] + bias;
            }
        }
    } else {                         // v -> vT4[h][tile][d][keyperm]
#pragma unroll
        for (int ct = 0; ct < 8; ++ct) {
            float bias = bv[ct * 16 + mr];
#pragma unroll
            for (int reg = 0; reg < 4; ++reg) {
                int m = w * 16 + quad * 4 + reg;
                int sub = m >> 6, ml = m & 63;
                T16[(ct * 16 + mr) * 136 + sub * 64 + keyperm(ml)] =
                    (_Float16)(acc[ct][reg] + bias);
            }
        }
        __syncthreads();
#pragma unroll
        for (int i = 0; i < 4; ++i) {
            int idx = t + i * 512;           // c(128) x sub(2) x seg(8)
            int c = idx >> 4, sub = (idx >> 3) & 1, seg = idx & 7;
            int h = c >> 4, d = c & 15;
            int tile = (flat & 63) * 2 + sub;
            *reinterpret_cast<h8*>(
                vT4 + ((size_t)(h * 128 + tile) * 16 + d) * 64 + seg * 8) =
                *reinterpret_cast<h8*>(&T16[c * 136 + sub * 64 + seg * 8]);
        }
    }
}

// ---------------------------------------------------------------------------
// Kernel 2: flash attention — EXACT R21 structure (best measured; frozen).
// 4 chains/wave, head-pinned XCD swizzle, setprio, 3-slot LDS combine.
// ---------------------------------------------------------------------------
#define LOADT(K0, K1, K2, K3, V0, V1, TILE)                                   \
    do {                                                                      \
        const _Float16* kp_ = kbase + (size_t)(TILE) * 1024;                  \
        const _Float16* vp_ = vbase + (size_t)(TILE) * 1024;                  \
        K0 = *reinterpret_cast<const h4*>(kp_);                               \
        K1 = *reinterpret_cast<const h4*>(kp_ + 256);                         \
        K2 = *reinterpret_cast<const h4*>(kp_ + 512);                         \
        K3 = *reinterpret_cast<const h4*>(kp_ + 768);                         \
        V0 = *reinterpret_cast<const h8*>(vp_);                               \
        V1 = *reinterpret_cast<const h8*>(vp_ + 32);                         \
    } while (0)

#define PROC_SUB(AQ, K0, K1, K2, K3, V0, V1, O, L)                            \
    do {                                                                      \
        f4 st0 = __builtin_amdgcn_mfma_f32_16x16x16f16(K0, AQ, fzero, 0, 0, 0); \
        f4 st1 = __builtin_amdgcn_mfma_f32_16x16x16f16(K1, AQ, fzero, 0, 0, 0); \
        f4 st2 = __builtin_amdgcn_mfma_f32_16x16x16f16(K2, AQ, fzero, 0, 0, 0); \
        f4 st3 = __builtin_amdgcn_mfma_f32_16x16x16f16(K3, AQ, fzero, 0, 0, 0); \
        H8U pa, pb;                                                           \
        pa.u[0] = __builtin_bit_cast(unsigned, __builtin_amdgcn_cvt_pkrtz(    \
            __builtin_amdgcn_exp2f(st0[0]), __builtin_amdgcn_exp2f(st0[1]))); \
        pa.u[1] = __builtin_bit_cast(unsigned, __builtin_amdgcn_cvt_pkrtz(    \
            __builtin_amdgcn_exp2f(st0[2]), __builtin_amdgcn_exp2f(st0[3]))); \
        pa.u[2] = __builtin_bit_cast(unsigned, __builtin_amdgcn_cvt_pkrtz(    \
            __builtin_amdgcn_exp2f(st1[0]), __builtin_amdgcn_exp2f(st1[1]))); \
        pa.u[3] = __builtin_bit_cast(unsigned, __builtin_amdgcn_cvt_pkrtz(    \
            __builtin_amdgcn_exp2f(st1[2]), __builtin_amdgcn_exp2f(st1[3]))); \
        pb.u[0] = __builtin_bit_cast(unsigned, __builtin_amdgcn_cvt_pkrtz(    \
            __builtin_amdgcn_exp2f(st2[0]), __builtin_amdgcn_exp2f(st2[1]))); \
        pb.u[1] = __builtin_bit_cast(unsigned, __builtin_amdgcn_cvt_pkrtz(    \
            __builtin_amdgcn_exp2f(st2[2]), __builtin_amdgcn_exp2f(st2[3]))); \
        pb.u[2] = __builtin_bit_cast(unsigned, __builtin_amdgcn_cvt_pkrtz(    \
            __builtin_amdgcn_exp2f(st3[0]), __builtin_amdgcn_exp2f(st3[1]))); \
        pb.u[3] = __builtin_bit_cast(unsigned, __builtin_amdgcn_cvt_pkrtz(    \
            __builtin_amdgcn_exp2f(st3[2]), __builtin_amdgcn_exp2f(st3[3]))); \
        O = __builtin_amdgcn_mfma_f32_16x16x32_f16(pa.v, V0, O, 0, 0, 0);     \
        L = __builtin_amdgcn_mfma_f32_16x16x32_f16(pa.v, vones, L, 0, 0, 0);  \
        O = __builtin_amdgcn_mfma_f32_16x16x32_f16(pb.v, V1, O, 0, 0, 0);     \
        L = __builtin_amdgcn_mfma_f32_16x16x32_f16(pb.v, vones, L, 0, 0, 0);  \
    } while (0)

#define COMBINE(OC, LC, CIDX)                                                 \
    do {                                                                      \
        _Pragma("unroll")                                                     \
        for (int reg = 0; reg < 4; ++reg) {                                   \
            float of = OC[reg] + Cmb[0][wq][lane][(CIDX)*4 + reg]             \
                               + Cmb[1][wq][lane][(CIDX)*4 + reg]             \
                               + Cmb[2][wq][lane][(CIDX)*4 + reg];            \
            float lf = LC[reg] + Cmb[0][wq][lane][16 + (CIDX)*4 + reg]        \
                               + Cmb[1][wq][lane][16 + (CIDX)*4 + reg]        \
                               + Cmb[2][wq][lane][16 + (CIDX)*4 + reg];       \
            att16[(size_t)(m0 + (CIDX)*16 + quad * 4 + reg) * 128             \
                  + hh * DHD + mr] = (_Float16)(of / lf);                     \
        }                                                                     \
    } while (0)

__global__ __launch_bounds__(512) void attn_kernel(
    const _Float16* __restrict__ qT, const _Float16* __restrict__ kT,
    const _Float16* __restrict__ vT4, const int* __restrict__ mask,
    _Float16* __restrict__ att16)
{
    __shared__ float Cmb[3][2][64][33];   // 3 writer groups x wq x lane x 32+pad

    // XCD swizzle: hw linear wg id; xcd slot = flat%8 == hh (K/V L2 locality).
    const int flat = blockIdx.x + 32 * blockIdx.y + 256 * blockIdx.z;
    const int hh = flat & 7;
    const int qt = (flat >> 3) & 31;
    const int b  = flat >> 8;

    const int t = threadIdx.x;
    const int w = t >> 6, lane = t & 63, quad = lane >> 4, mr = lane & 15;
    const int wq = w & 1;          // q sub-tile (64 rows each)
    const int g  = w >> 1;         // key-range quarter (0..3)
    const int m0 = b * SEQ + qt * 128 + wq * 64;

    if (mask[b * SEQ + qt * 128] == 0) return;

    int tv = mask[b * SEQ + lane * 64];
    const int ntiles = (int)__popcll(__ballot(tv != 0));   // 64 or 48
    const int quarter = ntiles >> 2;                        // 16 or 12 (even)
    const int tbeg = g * quarter;
    const int tend = tbeg + quarter;

    const h4 aQ0 = *reinterpret_cast<const h4*>(
        qT + ((size_t)hh * MROWS + m0 + mr) * DHD + quad * 4);
    const h4 aQ1 = *reinterpret_cast<const h4*>(
        qT + ((size_t)hh * MROWS + m0 + 16 + mr) * DHD + quad * 4);
    const h4 aQ2 = *reinterpret_cast<const h4*>(
        qT + ((size_t)hh * MROWS + m0 + 32 + mr) * DHD + quad * 4);
    const h4 aQ3 = *reinterpret_cast<const h4*>(
        qT + ((size_t)hh * MROWS + m0 + 48 + mr) * DHD + quad * 4);

    const _Float16* kbase = kT + ((size_t)hh * MROWS + b * SEQ + mr) * DHD + quad * 4;
    const _Float16* vbase = vT4 + ((size_t)(hh * 128 + b * 64) * 16 + mr) * 64 + quad * 8;

    const f4 fzero = {0.f, 0.f, 0.f, 0.f};
    const _Float16 one = (_Float16)1.0f;
    const h8 vones = {one, one, one, one, one, one, one, one};

    h4 ka0, ka1, ka2, ka3, kb0, kb1, kb2, kb3;
    h8 va0, va1, vb0, vb1;
    LOADT(ka0, ka1, ka2, ka3, va0, va1, tbeg);
    LOADT(kb0, kb1, kb2, kb3, vb0, vb1, tbeg + 1);

    f4 O0 = fzero, O1 = fzero, O2 = fzero, O3 = fzero;
    f4 L0 = fzero, L1 = fzero, L2 = fzero, L3 = fzero;

    for (int it = tbeg; it < tend; it += 2) {
        __builtin_amdgcn_s_setprio(1);
        PROC_SUB(aQ0, ka0, ka1, ka2, ka3, va0, va1, O0, L0);
        PROC_SUB(aQ1, ka0, ka1, ka2, ka3, va0, va1, O1, L1);
        PROC_SUB(aQ2, ka0, ka1, ka2, ka3, va0, va1, O2, L2);
        PROC_SUB(aQ3, ka0, ka1, ka2, ka3, va0, va1, O3, L3);
        __builtin_amdgcn_s_setprio(0);
        int nA = (it + 2 < tend) ? (it + 2) : it;
        LOADT(ka0, ka1, ka2, ka3, va0, va1, nA);

        __builtin_amdgcn_s_setprio(1);
        PROC_SUB(aQ0, kb0, kb1, kb2, kb3, vb0, vb1, O0, L0);
        PROC_SUB(aQ1, kb0, kb1, kb2, kb3, vb0, vb1, O1, L1);
        PROC_SUB(aQ2, kb0, kb1, kb2, kb3, vb0, vb1, O2, L2);
        PROC_SUB(aQ3, kb0, kb1, kb2, kb3, vb0, vb1, O3, L3);
        __builtin_amdgcn_s_setprio(0);
        int nB = (it + 3 < tend) ? (it + 3) : (it + 1);
        LOADT(kb0, kb1, kb2, kb3, vb0, vb1, nB);
    }

    if (g != 0) {
        float* dst = &Cmb[g - 1][wq][lane][0];
#pragma unroll
        for (int reg = 0; reg < 4; ++reg) {
            dst[reg]      = O0[reg];
            dst[4 + reg]  = O1[reg];
            dst[8 + reg]  = O2[reg];
            dst[12 + reg] = O3[reg];
            dst[16 + reg] = L0[reg];
            dst[20 + reg] = L1[reg];
            dst[24 + reg] = L2[reg];
            dst[28 + reg] = L3[reg];
        }
    }
    __syncthreads();
    if (g == 0) {
        COMBINE(O0, L0, 0);
        COMBINE(O1, L1, 1);
        COMBINE(O2, L2, 2);
        COMBINE(O3, L3, 3);
    }
}

// ---------------------------------------------------------------------------
// Kernel 3: out += att16 @ Wo — R21 shape (512 blocks x 4 waves, 64r x 32c),
// R25: Wo->LDS transpose packed (pairs of rows -> h2 dword stores).
// ---------------------------------------------------------------------------
__global__ __launch_bounds__(256) void outproj_kernel(
    const _Float16* __restrict__ att16, const float* __restrict__ Wo,
    const int* __restrict__ mask, float* __restrict__ out)
{
    __shared__ __align__(16) _Float16 Tw[32 * 136];   // Wo slice, transposed
    __shared__ __align__(16) float   To[64 * 36];     // att@Wo staging

    const int t = threadIdx.x;
    const int w = t >> 6, lane = t & 63, quad = lane >> 4, mr = lane & 15;
    const int row0 = blockIdx.x * 64;
    const int m0w  = row0 + w * 16;
    const int c0   = blockIdx.y * 32;

    if (mask[row0] == 0) return;     // out already zeroed by proj out-init

    // Wo slice (128k x 32c) -> Tw[c][k] f16, packed pair loads
    float4 wa[2], wb[2];
#pragma unroll
    for (int i = 0; i < 2; ++i) {
        int idx = t + i * 256;               // k2(64) x c4(8)
        int k2 = idx >> 3, c4 = idx & 7;
        wa[i] = *reinterpret_cast<const float4*>(Wo + (size_t)(2 * k2)     * 128 + c0 + c4 * 4);
        wb[i] = *reinterpret_cast<const float4*>(Wo + (size_t)(2 * k2 + 1) * 128 + c0 + c4 * 4);
    }
    h8 a[4];
#pragma unroll
    for (int ks = 0; ks < 4; ++ks)
        a[ks] = *reinterpret_cast<const h8*>(
            att16 + (size_t)(m0w + mr) * 128 + ks * 32 + quad * 8);
#pragma unroll
    for (int i = 0; i < 2; ++i) {
        int idx = t + i * 256;
        int k2 = idx >> 3, c4 = idx & 7;
        const float* fa = reinterpret_cast<const float*>(&wa[i]);
        const float* fb = reinterpret_cast<const float*>(&wb[i]);
#pragma unroll
        for (int j = 0; j < 4; ++j) {
            unsigned p = __builtin_bit_cast(unsigned,
                __builtin_amdgcn_cvt_pkrtz(fa[j], fb[j]));
            *reinterpret_cast<unsigned*>(&Tw[(c4 * 4 + j) * 136 + 2 * k2]) = p;
        }
    }
    __syncthreads();

    f4 acc[2];
#pragma unroll
    for (int ct = 0; ct < 2; ++ct) {
        f4 ac = {0.f, 0.f, 0.f, 0.f};
#pragma unroll
        for (int ks = 0; ks < 4; ++ks) {
            h8 bb = *reinterpret_cast<const h8*>(
                &Tw[(ct * 16 + mr) * 136 + ks * 32 + quad * 8]);
            ac = __builtin_amdgcn_mfma_f32_16x16x32_f16(a[ks], bb, ac, 0, 0, 0);
        }
        acc[ct] = ac;
    }

    // Stage att@Wo tile in LDS, then coalesced float4 RMW on out
#pragma unroll
    for (int ct = 0; ct < 2; ++ct) {
#pragma unroll
        for (int reg = 0; reg < 4; ++reg) {
            int lr = w * 16 + quad * 4 + reg;       // 0..63
            To[lr * 36 + ct * 16 + mr] = acc[ct][reg];
        }
    }
    __syncthreads();
#pragma unroll
    for (int i = 0; i < 2; ++i) {
        int idx = t + i * 256;                       // r(64) x c4(8)
        int r = idx >> 3, c4 = idx & 7;
        float4* dst = reinterpret_cast<float4*>(
            out + (size_t)(row0 + r) * 128 + c0 + c4 * 4);
        float4 o = *dst;
        float4 add = *reinterpret_cast<float4*>(&To[r * 36 + c4 * 4]);
        o.x += add.x; o.y += add.y; o.z += add.z; o.w += add.w;
        *dst = o;
    }
}

// ---------------------------------------------------------------------------
extern "C" void kernel_launch(void* const* d_in, const int* in_sizes, int n_in,
                              void* d_out, int out_size, void* d_ws, size_t ws_size,
                              hipStream_t stream) {
    const float* x    = (const float*)d_in[0];
    const int*   mask = (const int*)  d_in[1];
    const float* W1   = (const float*)d_in[2];
    const float* b1   = (const float*)d_in[3];
    const float* Wv   = (const float*)d_in[4];
    const float* bv   = (const float*)d_in[5];
    const float* Wo   = (const float*)d_in[6];
    const float* bo   = (const float*)d_in[7];
    float* out = (float*)d_out;

    _Float16* qT    = (_Float16*)d_ws;                     // [8][8192][16] = 2 MB
    _Float16* kT    = qT    + (size_t)NH * MROWS * DHD;    //                 2 MB
    _Float16* vT4   = kT    + (size_t)NH * MROWS * DHD;    // [8][128][16][64] = 2 MB
    _Float16* att16 = vT4   + (size_t)DIN * MROWS;         // [8192][128] =   2 MB

    proj_kernel<<<dim3(4, 64), 512, 0, stream>>>(
        x, mask, W1, Wv, b1, bv, bo, qT, kT, vT4, out);
    attn_kernel<<<dim3(SEQ / 128, NH, BATCH), 512, 0, stream>>>(
        qT, kT, vT4, mask, att16);
    outproj_kernel<<<dim3(MROWS / 64, 4), 256, 0, stream>>>(
        att16, Wo, mask, out);
}